// Round 5
// baseline (597.239 us; speedup 1.0000x reference)
//
#include <hip/hip_runtime.h>
#include <hip/hip_bf16.h>

#define B_SZ  4
#define T_SEQ 4096
#define NE    2048
#define HD    128
#define NROWS (B_SZ * T_SEQ)   // 16384
#define SPLITK 4

typedef __attribute__((ext_vector_type(4))) float f32x4;
typedef __attribute__((ext_vector_type(8))) short s16x8;

__device__ __forceinline__ ushort f2bf(float f) {
    __hip_bfloat16 h = __float2bfloat16(f);
    return *reinterpret_cast<ushort*>(&h);
}
__device__ __forceinline__ unsigned int pk2(float a, float b) {
    return (unsigned int)f2bf(a) | ((unsigned int)f2bf(b) << 16);
}

// ---------------- K0: W fp32 [2048][128] -> wt bf16 [384][2048] (B^T layout) --------
// Wq is pre-scaled by 1/sqrt(HD) so attention scores need no scale multiply.
__global__ __launch_bounds__(256) void wconv_kernel(
    const float* __restrict__ Wq, const float* __restrict__ Wk,
    const float* __restrict__ Wv, ushort* __restrict__ wt)
{
    __shared__ __align__(16) ushort tr[128][80];
    const int mat = blockIdx.y;
    const int k0  = blockIdx.x * 64;
    const float* W = (mat == 0) ? Wq : (mat == 1) ? Wk : Wv;
    const float scale = (mat == 0) ? 0.08838834764831845f : 1.0f;
    const int tid = threadIdx.x;

    #pragma unroll
    for (int p = 0; p < 32; p++) {
        const int idx = p * 256 + tid;
        const int k = idx >> 7, h = idx & 127;
        tr[h][k] = f2bf(W[(size_t)(k0 + k) * HD + h] * scale);
    }
    __syncthreads();
    const int h = tid >> 1, half = tid & 1;
    const uint4* src = (const uint4*)&tr[h][half * 32];
    uint4* dst = (uint4*)(wt + (size_t)(mat * HD + h) * NE + k0 + half * 32);
    #pragma unroll
    for (int j = 0; j < 4; j++) dst[j] = src[j];
}

// ---------------- K1: qkv = x @ [Wq|Wk|Wv], MFMA bf16, column-split ----------------
// block: 64 rows x 96 cols (blockIdx.y = col group); wave w: rows w*16..+15, 6 n-tiles
__global__ __launch_bounds__(256) void qkv_kernel(
    const float* __restrict__ x, const ushort* __restrict__ wt,
    ushort* __restrict__ q_b, ushort* __restrict__ k_b, ushort* __restrict__ vt)
{
    __shared__ __align__(16) ushort xa[2][64][72];

    const int tid  = threadIdx.x;
    const int wave = tid >> 6, lane = tid & 63;
    const int nn   = lane & 15, quad = lane >> 4;
    const int rows0 = blockIdx.x * 64;
    const int c0    = blockIdx.y * 96;

    f32x4 acc[6];
    #pragma unroll
    for (int nt = 0; nt < 6; nt++) acc[nt] = (f32x4){0.f, 0.f, 0.f, 0.f};

    const int srow = tid >> 2, skq = tid & 3;
    const float* xp = x + (size_t)(rows0 + srow) * NE + skq * 16;

    float4 xr[4];
    auto load_x = [&](int kc) {
        #pragma unroll
        for (int j = 0; j < 4; j++) xr[j] = *(const float4*)(xp + kc + j * 4);
    };
    auto write_x = [&](int buf) {
        uint4 w0, w1;
        w0.x = pk2(xr[0].x, xr[0].y); w0.y = pk2(xr[0].z, xr[0].w);
        w0.z = pk2(xr[1].x, xr[1].y); w0.w = pk2(xr[1].z, xr[1].w);
        w1.x = pk2(xr[2].x, xr[2].y); w1.y = pk2(xr[2].z, xr[2].w);
        w1.z = pk2(xr[3].x, xr[3].y); w1.w = pk2(xr[3].z, xr[3].w);
        *(uint4*)&xa[buf][srow][skq * 16]     = w0;
        *(uint4*)&xa[buf][srow][skq * 16 + 8] = w1;
    };

    load_x(0);
    write_x(0);

    for (int t = 0; t < 32; t++) {
        const int kc = t * 64;
        if (t + 1 < 32) load_x(kc + 64);
        __syncthreads();
        const int cb = t & 1;
        #pragma unroll
        for (int ks = 0; ks < 2; ks++) {
            const s16x8 af = *(const s16x8*)&xa[cb][wave * 16 + nn][ks * 32 + quad * 8];
            #pragma unroll
            for (int nt = 0; nt < 6; nt++) {
                const s16x8 bf = *(const s16x8*)&wt[(size_t)(c0 + nt * 16 + nn) * NE + kc + ks * 32 + quad * 8];
                acc[nt] = __builtin_amdgcn_mfma_f32_16x16x32_bf16(af, bf, acc[nt], 0, 0, 0);
            }
        }
        if (t + 1 < 32) write_x((t + 1) & 1);
    }

    #pragma unroll
    for (int nt = 0; nt < 6; nt++) {
        const int c = c0 + nt * 16 + nn;
        #pragma unroll
        for (int r = 0; r < 4; r++) {
            const int grow = rows0 + wave * 16 + quad * 4 + r;
            const ushort v = f2bf(acc[nt][r]);
            if (c < 128)       q_b[(size_t)grow * HD + c] = v;
            else if (c < 256)  k_b[(size_t)grow * HD + (c - 128)] = v;
            else               vt[(size_t)(c - 256) * NROWS + grow] = v;
        }
    }
}

// ---------------- K2: causal flash attention, split-K, barrier-free ----------------
// block = 1 wave (64 threads) = 16 q rows x one key-split. K/V read direct from
// global (L1/L2-hot). S^T = K Q^T so each lane owns one q-row's scores.
__global__ __launch_bounds__(64) void attn_kernel(
    const ushort* __restrict__ q_b, const ushort* __restrict__ k_b,
    const ushort* __restrict__ vt, float* __restrict__ o_part,
    float2* __restrict__ ml_part)
{
    __shared__ __align__(16) ushort pT[16][72];   // [q local][key in tile]

    const int qt = blockIdx.x;                 // 0..1023
    const int sp = blockIdx.y;                 // 0..SPLITK-1
    const int b  = qt >> 8;
    const int qrow0 = (qt & 255) * 16;
    const size_t bT = (size_t)b * T_SEQ;

    const int lane = threadIdx.x;
    const int nn = lane & 15, quad = lane >> 4;
    const int qglob = qrow0 + nn;

    s16x8 qfrag[4];
    #pragma unroll
    for (int ks = 0; ks < 4; ks++)
        qfrag[ks] = *(const s16x8*)&q_b[(bT + qrow0 + nn) * HD + ks * 32 + quad * 8];

    f32x4 o_acc[8];
    #pragma unroll
    for (int nt = 0; nt < 8; nt++) o_acc[nt] = (f32x4){0.f, 0.f, 0.f, 0.f};
    float m_i = -INFINITY, l_i = 0.0f;

    const int ntiles = (qrow0 >> 6) + 1;       // keys 0 .. qrow0+15

    const ushort* kbase = k_b + (bT + nn) * HD + quad * 8;
    const ushort* vbase = vt + (size_t)nn * NROWS + bT + quad * 8;

    for (int t = sp; t < ntiles; t += SPLITK) {
        const int s0 = t * 64;

        // S^T = K Q^T : lane owns q-row nn, 16 key scores (mt*16 + quad*4 + r)
        f32x4 sa[4];
        #pragma unroll
        for (int mt = 0; mt < 4; mt++) sa[mt] = (f32x4){0.f, 0.f, 0.f, 0.f};
        const ushort* kp = kbase + (size_t)s0 * HD;
        #pragma unroll
        for (int ks = 0; ks < 4; ks++)
            #pragma unroll
            for (int mt = 0; mt < 4; mt++) {
                const s16x8 af = *(const s16x8*)(kp + (size_t)(mt * 16) * HD + ks * 32);
                sa[mt] = __builtin_amdgcn_mfma_f32_16x16x32_bf16(af, qfrag[ks], sa[mt], 0, 0, 0);
            }

        // causal mask — needed iff this tile reaches above the q rows
        // (tile keys s0..s0+63 vs q rows qrow0..qrow0+15)
        if (s0 + 63 > qrow0) {
            #pragma unroll
            for (int mt = 0; mt < 4; mt++)
                #pragma unroll
                for (int r = 0; r < 4; r++)
                    if (s0 + mt * 16 + quad * 4 + r > qglob) sa[mt][r] = -INFINITY;
        }

        // online softmax: in-lane 16-value reduce + 2 cross-quad shuffles
        float rm = -INFINITY;
        #pragma unroll
        for (int mt = 0; mt < 4; mt++)
            #pragma unroll
            for (int r = 0; r < 4; r++) rm = fmaxf(rm, sa[mt][r]);
        rm = fmaxf(rm, __shfl_xor(rm, 16));
        rm = fmaxf(rm, __shfl_xor(rm, 32));
        const float mnew = fmaxf(m_i, rm);
        const float alpha = __expf(m_i - mnew);
        m_i = mnew;

        float p[4][4], rs = 0.0f;
        #pragma unroll
        for (int mt = 0; mt < 4; mt++)
            #pragma unroll
            for (int r = 0; r < 4; r++) {
                p[mt][r] = __expf(sa[mt][r] - mnew);
                rs += p[mt][r];
            }
        rs += __shfl_xor(rs, 16);
        rs += __shfl_xor(rs, 32);
        l_i = l_i * alpha + rs;

        // P -> LDS in A-layout rows: pT[q=nn][key]
        #pragma unroll
        for (int mt = 0; mt < 4; mt++) {
            uint2 w;
            w.x = pk2(p[mt][0], p[mt][1]);
            w.y = pk2(p[mt][2], p[mt][3]);
            *(uint2*)&pT[nn][mt * 16 + quad * 4] = w;
        }

        // broadcast alpha to O rows (row m = quad*4+r lives in lane m's softmax)
        float am[4];
        #pragma unroll
        for (int r = 0; r < 4; r++) am[r] = __shfl(alpha, quad * 4 + r);
        #pragma unroll
        for (int nt = 0; nt < 8; nt++) {
            o_acc[nt][0] *= am[0];
            o_acc[nt][1] *= am[1];
            o_acc[nt][2] *= am[2];
            o_acc[nt][3] *= am[3];
        }

        // O += P V
        s16x8 pf[2];
        pf[0] = *(const s16x8*)&pT[nn][quad * 8];
        pf[1] = *(const s16x8*)&pT[nn][32 + quad * 8];
        const ushort* vp = vbase + s0;
        #pragma unroll
        for (int nt = 0; nt < 8; nt++)
            #pragma unroll
            for (int kst = 0; kst < 2; kst++) {
                const s16x8 vb = *(const s16x8*)(vp + (size_t)(nt * 16) * NROWS + kst * 32);
                o_acc[nt] = __builtin_amdgcn_mfma_f32_16x16x32_bf16(pf[kst], vb, o_acc[nt], 0, 0, 0);
            }
    }

    // write partials (unnormalized O + per-row m,l)
    float* op = o_part + ((size_t)sp * NROWS + bT + qrow0 + quad * 4) * HD + nn;
    #pragma unroll
    for (int r = 0; r < 4; r++)
        #pragma unroll
        for (int nt = 0; nt < 8; nt++)
            op[(size_t)r * HD + nt * 16] = o_acc[nt][r];
    if (quad == 0)
        ml_part[(size_t)sp * NROWS + bT + qrow0 + nn] = make_float2(m_i, l_i);
}

// ---------------- K3: split-K combine ----------------
__global__ __launch_bounds__(256) void combine_kernel(
    const float* __restrict__ o_part, const float2* __restrict__ ml_part,
    float* __restrict__ out)
{
    const int idx = blockIdx.x * 256 + threadIdx.x;  // NROWS*64 threads
    const int row = idx >> 6;
    const int c   = (idx & 63) * 2;

    float m[SPLITK], l[SPLITK];
    float M = -INFINITY;
    #pragma unroll
    for (int s = 0; s < SPLITK; s++) {
        const float2 t = ml_part[(size_t)s * NROWS + row];
        m[s] = t.x; l[s] = t.y;
        M = fmaxf(M, m[s]);
    }
    float L = 0.0f, w[SPLITK];
    #pragma unroll
    for (int s = 0; s < SPLITK; s++) {
        w[s] = __expf(m[s] - M);
        L += w[s] * l[s];
    }
    const float inv = 1.0f / L;
    float ox = 0.0f, oy = 0.0f;
    #pragma unroll
    for (int s = 0; s < SPLITK; s++) {
        const float2 po = *(const float2*)(o_part + ((size_t)s * NROWS + row) * HD + c);
        ox += w[s] * po.x;
        oy += w[s] * po.y;
    }
    out[(size_t)row * HD + c]     = ox * inv;
    out[(size_t)row * HD + c + 1] = oy * inv;
}

extern "C" void kernel_launch(void* const* d_in, const int* in_sizes, int n_in,
                              void* d_out, int out_size, void* d_ws, size_t ws_size,
                              hipStream_t stream) {
    const float* x  = (const float*)d_in[0];
    const float* Wq = (const float*)d_in[1];
    const float* Wk = (const float*)d_in[2];
    const float* Wv = (const float*)d_in[3];

    ushort* q_b = (ushort*)d_ws;                       // 4 MB
    ushort* k_b = q_b + (size_t)NROWS * HD;            // 4 MB
    ushort* vtp = k_b + (size_t)NROWS * HD;            // 4 MB (v transposed [h][row])
    ushort* wt  = vtp + (size_t)HD * NROWS;            // 1.5 MB ([384][2048])
    float*  o_part  = (float*)(wt + (size_t)384 * NE); // 32 MB
    float2* ml_part = (float2*)(o_part + (size_t)SPLITK * NROWS * HD);  // 512 KB

    wconv_kernel<<<dim3(32, 3), dim3(256), 0, stream>>>(Wq, Wk, Wv, wt);
    qkv_kernel<<<dim3(256, 4), dim3(256), 0, stream>>>(x, wt, q_b, k_b, vtp);
    attn_kernel<<<dim3(1024, SPLITK), dim3(64), 0, stream>>>(q_b, k_b, vtp, o_part, ml_part);
    combine_kernel<<<dim3((NROWS * 64) / 256), dim3(256), 0, stream>>>(
        o_part, ml_part, (float*)d_out);
}

// Round 6
// 583.213 us; speedup vs baseline: 1.0240x; 1.0240x over previous
//
#include <hip/hip_runtime.h>
#include <hip/hip_bf16.h>

#define B_SZ  4
#define T_SEQ 4096
#define NE    2048
#define HD    128
#define NROWS (B_SZ * T_SEQ)   // 16384
#define SPLITK 8

typedef __attribute__((ext_vector_type(4))) float f32x4;
typedef __attribute__((ext_vector_type(8))) short s16x8;

__device__ __forceinline__ ushort f2bf(float f) {
    __hip_bfloat16 h = __float2bfloat16(f);
    return *reinterpret_cast<ushort*>(&h);
}
__device__ __forceinline__ float bf2f(ushort u) {
    return __uint_as_float(((unsigned int)u) << 16);
}
__device__ __forceinline__ unsigned int pk2(float a, float b) {
    return (unsigned int)f2bf(a) | ((unsigned int)f2bf(b) << 16);
}

// ---------------- K0: W fp32 [2048][128] -> wt bf16 [384][2048] (B^T layout) --------
// Wq is pre-scaled by 1/sqrt(HD) so attention scores need no scale multiply.
__global__ __launch_bounds__(256) void wconv_kernel(
    const float* __restrict__ Wq, const float* __restrict__ Wk,
    const float* __restrict__ Wv, ushort* __restrict__ wt)
{
    __shared__ __align__(16) ushort tr[128][80];
    const int mat = blockIdx.y;
    const int k0  = blockIdx.x * 64;
    const float* W = (mat == 0) ? Wq : (mat == 1) ? Wk : Wv;
    const float scale = (mat == 0) ? 0.08838834764831845f : 1.0f;
    const int tid = threadIdx.x;

    #pragma unroll
    for (int p = 0; p < 32; p++) {
        const int idx = p * 256 + tid;
        const int k = idx >> 7, h = idx & 127;
        tr[h][k] = f2bf(W[(size_t)(k0 + k) * HD + h] * scale);
    }
    __syncthreads();
    const int h = tid >> 1, half = tid & 1;
    const uint4* src = (const uint4*)&tr[h][half * 32];
    uint4* dst = (uint4*)(wt + (size_t)(mat * HD + h) * NE + k0 + half * 32);
    #pragma unroll
    for (int j = 0; j < 4; j++) dst[j] = src[j];
}

// ---------------- K1: qkv = x @ [Wq|Wk|Wv], MFMA bf16 ----------------
// block: 32 rows x 384 cols, grid 512 (2 blocks/CU). wave w: 2 mt x 6 nt
// (rows 0..31, cols w*96..+95). x read once from HBM; wt from L2.
__global__ __launch_bounds__(256, 2) void qkv_kernel(
    const float* __restrict__ x, const ushort* __restrict__ wt,
    ushort* __restrict__ q_b, ushort* __restrict__ k_b, ushort* __restrict__ vt)
{
    __shared__ __align__(16) ushort xa[2][32][72];

    const int tid  = threadIdx.x;
    const int wave = tid >> 6, lane = tid & 63;
    const int nn   = lane & 15, quad = lane >> 4;
    const int rows0 = blockIdx.x * 32;
    const int c0    = wave * 96;

    f32x4 acc[2][6];
    #pragma unroll
    for (int mt = 0; mt < 2; mt++)
        #pragma unroll
        for (int nt = 0; nt < 6; nt++) acc[mt][nt] = (f32x4){0.f, 0.f, 0.f, 0.f};

    // staging: thread -> (row, 8-wide k chunk): 32x64 fp32 -> bf16
    const int srow = tid >> 3, skq = tid & 7;
    const float* xp = x + (size_t)(rows0 + srow) * NE + skq * 8;

    float4 xr0, xr1;
    auto load_x = [&](int kc) {
        xr0 = *(const float4*)(xp + kc);
        xr1 = *(const float4*)(xp + kc + 4);
    };
    auto write_x = [&](int buf) {
        uint4 w;
        w.x = pk2(xr0.x, xr0.y); w.y = pk2(xr0.z, xr0.w);
        w.z = pk2(xr1.x, xr1.y); w.w = pk2(xr1.z, xr1.w);
        *(uint4*)&xa[buf][srow][skq * 8] = w;
    };

    load_x(0);
    write_x(0);

    for (int t = 0; t < 32; t++) {
        const int kc = t * 64;
        if (t + 1 < 32) load_x(kc + 64);
        __syncthreads();
        const int cb = t & 1;
        #pragma unroll
        for (int ks = 0; ks < 2; ks++) {
            s16x8 af[2], bf[6];
            #pragma unroll
            for (int mt = 0; mt < 2; mt++)
                af[mt] = *(const s16x8*)&xa[cb][mt * 16 + nn][ks * 32 + quad * 8];
            #pragma unroll
            for (int nt = 0; nt < 6; nt++)
                bf[nt] = *(const s16x8*)&wt[(size_t)(c0 + nt * 16 + nn) * NE + kc + ks * 32 + quad * 8];
            #pragma unroll
            for (int mt = 0; mt < 2; mt++)
                #pragma unroll
                for (int nt = 0; nt < 6; nt++)
                    acc[mt][nt] = __builtin_amdgcn_mfma_f32_16x16x32_bf16(
                        af[mt], bf[nt], acc[mt][nt], 0, 0, 0);
        }
        if (t + 1 < 32) write_x((t + 1) & 1);
    }

    #pragma unroll
    for (int mt = 0; mt < 2; mt++)
        #pragma unroll
        for (int nt = 0; nt < 6; nt++) {
            const int c = c0 + nt * 16 + nn;
            #pragma unroll
            for (int r = 0; r < 4; r++) {
                const int grow = rows0 + mt * 16 + quad * 4 + r;
                const ushort v = f2bf(acc[mt][nt][r]);
                if (c < 128)       q_b[(size_t)grow * HD + c] = v;
                else if (c < 256)  k_b[(size_t)grow * HD + (c - 128)] = v;
                else               vt[(size_t)(c - 256) * NROWS + grow] = v;
            }
        }
}

// ---------------- K2: causal flash attention, split-K, barrier-free ----------------
// 256-thread block = 4 independent waves, each owning one 16-row q-tile x one
// key-split. K/V read direct from global (L1/L2-hot). S^T = K Q^T so each lane
// owns one full q-row's scores.
__global__ __launch_bounds__(256, 8) void attn_kernel(
    const ushort* __restrict__ q_b, const ushort* __restrict__ k_b,
    const ushort* __restrict__ vt, ushort* __restrict__ o_part,
    float2* __restrict__ ml_part)
{
    __shared__ __align__(16) ushort pT[4][16][72];   // [wave][q local][key in tile]

    const int wave = threadIdx.x >> 6;
    const int lane = threadIdx.x & 63;
    const int qt = blockIdx.x * 4 + wave;      // 0..1023
    const int sp = blockIdx.y;                 // 0..SPLITK-1
    const int b  = qt >> 8;
    const int qrow0 = (qt & 255) * 16;
    const size_t bT = (size_t)b * T_SEQ;

    const int nn = lane & 15, quad = lane >> 4;
    const int qglob = qrow0 + nn;

    s16x8 qfrag[4];
    #pragma unroll
    for (int ks = 0; ks < 4; ks++)
        qfrag[ks] = *(const s16x8*)&q_b[(bT + qrow0 + nn) * HD + ks * 32 + quad * 8];

    f32x4 o_acc[8];
    #pragma unroll
    for (int nt = 0; nt < 8; nt++) o_acc[nt] = (f32x4){0.f, 0.f, 0.f, 0.f};
    float m_i = -INFINITY, l_i = 0.0f;

    const int ntiles = (qrow0 >> 6) + 1;       // keys 0 .. qrow0+15

    const ushort* kbase = k_b + (bT + nn) * HD + quad * 8;
    const ushort* vbase = vt + (size_t)nn * NROWS + bT + quad * 8;

    for (int t = sp; t < ntiles; t += SPLITK) {
        const int s0 = t * 64;

        // S^T = K Q^T : lane owns q-row nn, 16 key scores (mt*16 + quad*4 + r)
        f32x4 sa[4];
        #pragma unroll
        for (int mt = 0; mt < 4; mt++) sa[mt] = (f32x4){0.f, 0.f, 0.f, 0.f};
        const ushort* kp = kbase + (size_t)s0 * HD;
        #pragma unroll
        for (int ks = 0; ks < 4; ks++)
            #pragma unroll
            for (int mt = 0; mt < 4; mt++) {
                const s16x8 af = *(const s16x8*)(kp + (size_t)(mt * 16) * HD + ks * 32);
                sa[mt] = __builtin_amdgcn_mfma_f32_16x16x32_bf16(af, qfrag[ks], sa[mt], 0, 0, 0);
            }

        // causal mask — needed iff this tile reaches above the q rows
        if (s0 + 63 > qrow0) {
            #pragma unroll
            for (int mt = 0; mt < 4; mt++)
                #pragma unroll
                for (int r = 0; r < 4; r++)
                    if (s0 + mt * 16 + quad * 4 + r > qglob) sa[mt][r] = -INFINITY;
        }

        // online softmax: in-lane 16-value reduce + 2 cross-quad shuffles
        float rm = -INFINITY;
        #pragma unroll
        for (int mt = 0; mt < 4; mt++)
            #pragma unroll
            for (int r = 0; r < 4; r++) rm = fmaxf(rm, sa[mt][r]);
        rm = fmaxf(rm, __shfl_xor(rm, 16));
        rm = fmaxf(rm, __shfl_xor(rm, 32));
        const float mnew = fmaxf(m_i, rm);
        const float alpha = __expf(m_i - mnew);
        m_i = mnew;

        float p[4][4], rs = 0.0f;
        #pragma unroll
        for (int mt = 0; mt < 4; mt++)
            #pragma unroll
            for (int r = 0; r < 4; r++) {
                p[mt][r] = __expf(sa[mt][r] - mnew);
                rs += p[mt][r];
            }
        rs += __shfl_xor(rs, 16);
        rs += __shfl_xor(rs, 32);
        l_i = l_i * alpha + rs;

        // P -> LDS in A-layout rows: pT[wave][q=nn][key]
        #pragma unroll
        for (int mt = 0; mt < 4; mt++) {
            uint2 w;
            w.x = pk2(p[mt][0], p[mt][1]);
            w.y = pk2(p[mt][2], p[mt][3]);
            *(uint2*)&pT[wave][nn][mt * 16 + quad * 4] = w;
        }

        // broadcast alpha to O rows (row m = quad*4+r lives in lane m's softmax)
        float am[4];
        #pragma unroll
        for (int r = 0; r < 4; r++) am[r] = __shfl(alpha, quad * 4 + r);
        #pragma unroll
        for (int nt = 0; nt < 8; nt++) {
            o_acc[nt][0] *= am[0];
            o_acc[nt][1] *= am[1];
            o_acc[nt][2] *= am[2];
            o_acc[nt][3] *= am[3];
        }

        // O += P V
        s16x8 pf[2];
        pf[0] = *(const s16x8*)&pT[wave][nn][quad * 8];
        pf[1] = *(const s16x8*)&pT[wave][nn][32 + quad * 8];
        const ushort* vp = vbase + s0;
        #pragma unroll
        for (int nt = 0; nt < 8; nt++)
            #pragma unroll
            for (int kst = 0; kst < 2; kst++) {
                const s16x8 vb = *(const s16x8*)(vp + (size_t)(nt * 16) * NROWS + kst * 32);
                o_acc[nt] = __builtin_amdgcn_mfma_f32_16x16x32_bf16(pf[kst], vb, o_acc[nt], 0, 0, 0);
            }
    }

    // write partials (unnormalized O as bf16 + per-row m,l)
    ushort* op = o_part + ((size_t)sp * NROWS + bT + qrow0 + quad * 4) * HD + nn;
    #pragma unroll
    for (int r = 0; r < 4; r++)
        #pragma unroll
        for (int nt = 0; nt < 8; nt++)
            op[(size_t)r * HD + nt * 16] = f2bf(o_acc[nt][r]);
    if (quad == 0)
        ml_part[(size_t)sp * NROWS + bT + qrow0 + nn] = make_float2(m_i, l_i);
}

// ---------------- K3: split-K combine ----------------
__global__ __launch_bounds__(256) void combine_kernel(
    const ushort* __restrict__ o_part, const float2* __restrict__ ml_part,
    float* __restrict__ out)
{
    const int idx = blockIdx.x * 256 + threadIdx.x;  // NROWS*64 threads
    const int row = idx >> 6;
    const int c   = (idx & 63) * 2;

    float m[SPLITK], l[SPLITK];
    float M = -INFINITY;
    #pragma unroll
    for (int s = 0; s < SPLITK; s++) {
        const float2 t = ml_part[(size_t)s * NROWS + row];
        m[s] = t.x; l[s] = t.y;
        M = fmaxf(M, m[s]);
    }
    float L = 0.0f, w[SPLITK];
    #pragma unroll
    for (int s = 0; s < SPLITK; s++) {
        w[s] = __expf(m[s] - M);
        L += w[s] * l[s];
    }
    const float inv = 1.0f / L;
    float ox = 0.0f, oy = 0.0f;
    #pragma unroll
    for (int s = 0; s < SPLITK; s++) {
        const ushort* po = o_part + ((size_t)s * NROWS + row) * HD + c;
        ox += w[s] * bf2f(po[0]);
        oy += w[s] * bf2f(po[1]);
    }
    out[(size_t)row * HD + c]     = ox * inv;
    out[(size_t)row * HD + c + 1] = oy * inv;
}

extern "C" void kernel_launch(void* const* d_in, const int* in_sizes, int n_in,
                              void* d_out, int out_size, void* d_ws, size_t ws_size,
                              hipStream_t stream) {
    const float* x  = (const float*)d_in[0];
    const float* Wq = (const float*)d_in[1];
    const float* Wk = (const float*)d_in[2];
    const float* Wv = (const float*)d_in[3];

    ushort* q_b = (ushort*)d_ws;                       // 4 MB
    ushort* k_b = q_b + (size_t)NROWS * HD;            // 4 MB
    ushort* vtp = k_b + (size_t)NROWS * HD;            // 4 MB (v transposed [h][row])
    ushort* wt  = vtp + (size_t)HD * NROWS;            // 1.5 MB ([384][2048])
    ushort* o_part  = wt + (size_t)384 * NE;           // 32 MB (bf16 partials)
    float2* ml_part = (float2*)(o_part + (size_t)SPLITK * NROWS * HD);  // 1 MB

    wconv_kernel<<<dim3(32, 3), dim3(256), 0, stream>>>(Wq, Wk, Wv, wt);
    qkv_kernel<<<dim3(512), dim3(256), 0, stream>>>(x, wt, q_b, k_b, vtp);
    attn_kernel<<<dim3(256, SPLITK), dim3(256), 0, stream>>>(q_b, k_b, vtp, o_part, ml_part);
    combine_kernel<<<dim3((NROWS * 64) / 256), dim3(256), 0, stream>>>(
        o_part, ml_part, (float*)d_out);
}

// Round 7
// 459.428 us; speedup vs baseline: 1.3000x; 1.2694x over previous
//
#include <hip/hip_runtime.h>
#include <hip/hip_bf16.h>

#define B_SZ  4
#define T_SEQ 4096
#define NE    2048
#define HD    128
#define NROWS (B_SZ * T_SEQ)   // 16384
#define SPLITK 8

typedef __attribute__((ext_vector_type(4))) float f32x4;
typedef __attribute__((ext_vector_type(8))) short s16x8;

__device__ __forceinline__ ushort f2bf(float f) {
    __hip_bfloat16 h = __float2bfloat16(f);
    return *reinterpret_cast<ushort*>(&h);
}
__device__ __forceinline__ float bf2f(ushort u) {
    return __uint_as_float(((unsigned int)u) << 16);
}
__device__ __forceinline__ unsigned int pk2(float a, float b) {
    return (unsigned int)f2bf(a) | ((unsigned int)f2bf(b) << 16);
}

// ---------------- K0: W fp32 [2048][128] -> wt bf16 [384][2048] (B^T layout) --------
// Wq is pre-scaled by 1/sqrt(HD) so attention scores need no scale multiply.
__global__ __launch_bounds__(256) void wconv_kernel(
    const float* __restrict__ Wq, const float* __restrict__ Wk,
    const float* __restrict__ Wv, ushort* __restrict__ wt)
{
    __shared__ __align__(16) ushort tr[128][80];
    const int mat = blockIdx.y;
    const int k0  = blockIdx.x * 64;
    const float* W = (mat == 0) ? Wq : (mat == 1) ? Wk : Wv;
    const float scale = (mat == 0) ? 0.08838834764831845f : 1.0f;
    const int tid = threadIdx.x;

    #pragma unroll
    for (int p = 0; p < 32; p++) {
        const int idx = p * 256 + tid;
        const int k = idx >> 7, h = idx & 127;
        tr[h][k] = f2bf(W[(size_t)(k0 + k) * HD + h] * scale);
    }
    __syncthreads();
    const int h = tid >> 1, half = tid & 1;
    const uint4* src = (const uint4*)&tr[h][half * 32];
    uint4* dst = (uint4*)(wt + (size_t)(mat * HD + h) * NE + k0 + half * 32);
    #pragma unroll
    for (int j = 0; j < 4; j++) dst[j] = src[j];
}

// ---------------- K1: qkv = x @ [Wq|Wk|Wv], MFMA bf16 ----------------
// block: 64 rows x 384 cols, grid 256. wave w: 4 mt x 6 nt (cols w*96..+95).
// B fragments register-prefetched one k-step ahead to hide L2 latency.
__global__ __launch_bounds__(256) void qkv_kernel(
    const float* __restrict__ x, const ushort* __restrict__ wt,
    ushort* __restrict__ q_b, ushort* __restrict__ k_b, ushort* __restrict__ vt)
{
    __shared__ __align__(16) ushort xa[2][64][72];

    const int tid  = threadIdx.x;
    const int wave = tid >> 6, lane = tid & 63;
    const int nn   = lane & 15, quad = lane >> 4;
    const int rows0 = blockIdx.x * 64;
    const int c0    = wave * 96;

    f32x4 acc[4][6];
    #pragma unroll
    for (int mt = 0; mt < 4; mt++)
        #pragma unroll
        for (int nt = 0; nt < 6; nt++) acc[mt][nt] = (f32x4){0.f, 0.f, 0.f, 0.f};

    // staging: thread -> (row, 16-wide k chunk)
    const int srow = tid >> 2, skq = tid & 3;
    const float* xp = x + (size_t)(rows0 + srow) * NE + skq * 16;

    float4 xr[4];
    auto load_x = [&](int kc) {
        #pragma unroll
        for (int j = 0; j < 4; j++) xr[j] = *(const float4*)(xp + kc + j * 4);
    };
    auto write_x = [&](int buf) {
        uint4 w0, w1;
        w0.x = pk2(xr[0].x, xr[0].y); w0.y = pk2(xr[0].z, xr[0].w);
        w0.z = pk2(xr[1].x, xr[1].y); w0.w = pk2(xr[1].z, xr[1].w);
        w1.x = pk2(xr[2].x, xr[2].y); w1.y = pk2(xr[2].z, xr[2].w);
        w1.z = pk2(xr[3].x, xr[3].y); w1.w = pk2(xr[3].z, xr[3].w);
        *(uint4*)&xa[buf][srow][skq * 16]     = w0;
        *(uint4*)&xa[buf][srow][skq * 16 + 8] = w1;
    };

    // per-wave B row pointers (k-contiguous)
    const ushort* wrow[6];
    #pragma unroll
    for (int nt = 0; nt < 6; nt++)
        wrow[nt] = wt + (size_t)(c0 + nt * 16 + nn) * NE + quad * 8;

    load_x(0);
    write_x(0);

    // prefetch B for (t=0, ks=0)
    s16x8 bnow[6], bnext[6];
    #pragma unroll
    for (int nt = 0; nt < 6; nt++) bnow[nt] = *(const s16x8*)(wrow[nt]);

    for (int t = 0; t < 32; t++) {
        const int kc = t * 64;
        if (t + 1 < 32) load_x(kc + 64);
        __syncthreads();
        const int cb = t & 1;
        #pragma unroll
        for (int ks = 0; ks < 2; ks++) {
            const int nk = kc + ks * 32 + 32;       // next B k-offset
            if (nk < NE) {
                #pragma unroll
                for (int nt = 0; nt < 6; nt++)
                    bnext[nt] = *(const s16x8*)(wrow[nt] + nk);
            }
            s16x8 af[4];
            #pragma unroll
            for (int mt = 0; mt < 4; mt++)
                af[mt] = *(const s16x8*)&xa[cb][mt * 16 + nn][ks * 32 + quad * 8];
            #pragma unroll
            for (int mt = 0; mt < 4; mt++)
                #pragma unroll
                for (int nt = 0; nt < 6; nt++)
                    acc[mt][nt] = __builtin_amdgcn_mfma_f32_16x16x32_bf16(
                        af[mt], bnow[nt], acc[mt][nt], 0, 0, 0);
            #pragma unroll
            for (int nt = 0; nt < 6; nt++) bnow[nt] = bnext[nt];
        }
        if (t + 1 < 32) write_x((t + 1) & 1);
    }

    #pragma unroll
    for (int mt = 0; mt < 4; mt++)
        #pragma unroll
        for (int nt = 0; nt < 6; nt++) {
            const int c = c0 + nt * 16 + nn;
            #pragma unroll
            for (int r = 0; r < 4; r++) {
                const int grow = rows0 + mt * 16 + quad * 4 + r;
                const ushort v = f2bf(acc[mt][nt][r]);
                if (c < 128)       q_b[(size_t)grow * HD + c] = v;
                else if (c < 256)  k_b[(size_t)grow * HD + (c - 128)] = v;
                else               vt[(size_t)(c - 256) * NROWS + grow] = v;
            }
        }
}

// ---------------- K2: causal flash attention, split-K, barrier-free ----------------
// 256-thread block = 4 independent waves, each owning one 16-row q-tile x one
// key-split. K/V read direct from global (L1/L2-hot). S^T = K Q^T so each lane
// owns one full q-row's scores. launch_bounds(256,4): 128-reg cap, NO spills.
__global__ __launch_bounds__(256, 4) void attn_kernel(
    const ushort* __restrict__ q_b, const ushort* __restrict__ k_b,
    const ushort* __restrict__ vt, ushort* __restrict__ o_part,
    float2* __restrict__ ml_part)
{
    __shared__ __align__(16) ushort pT[4][16][72];   // [wave][q local][key in tile]

    const int wave = threadIdx.x >> 6;
    const int lane = threadIdx.x & 63;
    const int qt = blockIdx.x * 4 + wave;      // 0..1023
    const int sp = blockIdx.y;                 // 0..SPLITK-1
    const int b  = qt >> 8;
    const int qrow0 = (qt & 255) * 16;
    const size_t bT = (size_t)b * T_SEQ;

    const int nn = lane & 15, quad = lane >> 4;
    const int qglob = qrow0 + nn;

    s16x8 qfrag[4];
    #pragma unroll
    for (int ks = 0; ks < 4; ks++)
        qfrag[ks] = *(const s16x8*)&q_b[(bT + qrow0 + nn) * HD + ks * 32 + quad * 8];

    f32x4 o_acc[8];
    #pragma unroll
    for (int nt = 0; nt < 8; nt++) o_acc[nt] = (f32x4){0.f, 0.f, 0.f, 0.f};
    float m_i = -INFINITY, l_i = 0.0f;

    const int ntiles = (qrow0 >> 6) + 1;       // keys 0 .. qrow0+15

    const ushort* kbase = k_b + (bT + nn) * HD + quad * 8;
    const ushort* vbase = vt + (size_t)nn * NROWS + bT + quad * 8;

    for (int t = sp; t < ntiles; t += SPLITK) {
        const int s0 = t * 64;

        // S^T = K Q^T : lane owns q-row nn, 16 key scores (mt*16 + quad*4 + r)
        f32x4 sa[4];
        #pragma unroll
        for (int mt = 0; mt < 4; mt++) sa[mt] = (f32x4){0.f, 0.f, 0.f, 0.f};
        const ushort* kp = kbase + (size_t)s0 * HD;
        #pragma unroll
        for (int ks = 0; ks < 4; ks++)
            #pragma unroll
            for (int mt = 0; mt < 4; mt++) {
                const s16x8 af = *(const s16x8*)(kp + (size_t)(mt * 16) * HD + ks * 32);
                sa[mt] = __builtin_amdgcn_mfma_f32_16x16x32_bf16(af, qfrag[ks], sa[mt], 0, 0, 0);
            }

        // causal mask — needed iff this tile reaches above the q rows
        if (s0 + 63 > qrow0) {
            #pragma unroll
            for (int mt = 0; mt < 4; mt++)
                #pragma unroll
                for (int r = 0; r < 4; r++)
                    if (s0 + mt * 16 + quad * 4 + r > qglob) sa[mt][r] = -INFINITY;
        }

        // online softmax: in-lane 16-value reduce + 2 cross-quad shuffles
        float rm = -INFINITY;
        #pragma unroll
        for (int mt = 0; mt < 4; mt++)
            #pragma unroll
            for (int r = 0; r < 4; r++) rm = fmaxf(rm, sa[mt][r]);
        rm = fmaxf(rm, __shfl_xor(rm, 16));
        rm = fmaxf(rm, __shfl_xor(rm, 32));
        const float mnew = fmaxf(m_i, rm);
        const float alpha = __expf(m_i - mnew);
        m_i = mnew;

        float p[4][4], rs = 0.0f;
        #pragma unroll
        for (int mt = 0; mt < 4; mt++)
            #pragma unroll
            for (int r = 0; r < 4; r++) {
                p[mt][r] = __expf(sa[mt][r] - mnew);
                rs += p[mt][r];
            }
        rs += __shfl_xor(rs, 16);
        rs += __shfl_xor(rs, 32);
        l_i = l_i * alpha + rs;

        // P -> LDS in A-layout rows: pT[wave][q=nn][key]
        #pragma unroll
        for (int mt = 0; mt < 4; mt++) {
            uint2 w;
            w.x = pk2(p[mt][0], p[mt][1]);
            w.y = pk2(p[mt][2], p[mt][3]);
            *(uint2*)&pT[wave][nn][mt * 16 + quad * 4] = w;
        }

        // broadcast alpha to O rows (row m = quad*4+r lives in lane m's softmax)
        float am[4];
        #pragma unroll
        for (int r = 0; r < 4; r++) am[r] = __shfl(alpha, quad * 4 + r);
        #pragma unroll
        for (int nt = 0; nt < 8; nt++) {
            o_acc[nt][0] *= am[0];
            o_acc[nt][1] *= am[1];
            o_acc[nt][2] *= am[2];
            o_acc[nt][3] *= am[3];
        }

        // O += P V
        s16x8 pf[2];
        pf[0] = *(const s16x8*)&pT[wave][nn][quad * 8];
        pf[1] = *(const s16x8*)&pT[wave][nn][32 + quad * 8];
        const ushort* vp = vbase + s0;
        #pragma unroll
        for (int nt = 0; nt < 8; nt++)
            #pragma unroll
            for (int kst = 0; kst < 2; kst++) {
                const s16x8 vb = *(const s16x8*)(vp + (size_t)(nt * 16) * NROWS + kst * 32);
                o_acc[nt] = __builtin_amdgcn_mfma_f32_16x16x32_bf16(pf[kst], vb, o_acc[nt], 0, 0, 0);
            }
    }

    // write partials (unnormalized O as bf16 + per-row m,l)
    ushort* op = o_part + ((size_t)sp * NROWS + bT + qrow0 + quad * 4) * HD + nn;
    #pragma unroll
    for (int r = 0; r < 4; r++)
        #pragma unroll
        for (int nt = 0; nt < 8; nt++)
            op[(size_t)r * HD + nt * 16] = f2bf(o_acc[nt][r]);
    if (quad == 0)
        ml_part[(size_t)sp * NROWS + bT + qrow0 + nn] = make_float2(m_i, l_i);
}

// ---------------- K3: split-K combine ----------------
__global__ __launch_bounds__(256) void combine_kernel(
    const ushort* __restrict__ o_part, const float2* __restrict__ ml_part,
    float* __restrict__ out)
{
    const int idx = blockIdx.x * 256 + threadIdx.x;  // NROWS*64 threads
    const int row = idx >> 6;
    const int c   = (idx & 63) * 2;

    float m[SPLITK], l[SPLITK];
    float M = -INFINITY;
    #pragma unroll
    for (int s = 0; s < SPLITK; s++) {
        const float2 t = ml_part[(size_t)s * NROWS + row];
        m[s] = t.x; l[s] = t.y;
        M = fmaxf(M, m[s]);
    }
    float L = 0.0f, w[SPLITK];
    #pragma unroll
    for (int s = 0; s < SPLITK; s++) {
        w[s] = __expf(m[s] - M);
        L += w[s] * l[s];
    }
    const float inv = 1.0f / L;
    float ox = 0.0f, oy = 0.0f;
    #pragma unroll
    for (int s = 0; s < SPLITK; s++) {
        const ushort* po = o_part + ((size_t)s * NROWS + row) * HD + c;
        ox += w[s] * bf2f(po[0]);
        oy += w[s] * bf2f(po[1]);
    }
    out[(size_t)row * HD + c]     = ox * inv;
    out[(size_t)row * HD + c + 1] = oy * inv;
}

extern "C" void kernel_launch(void* const* d_in, const int* in_sizes, int n_in,
                              void* d_out, int out_size, void* d_ws, size_t ws_size,
                              hipStream_t stream) {
    const float* x  = (const float*)d_in[0];
    const float* Wq = (const float*)d_in[1];
    const float* Wk = (const float*)d_in[2];
    const float* Wv = (const float*)d_in[3];

    ushort* q_b = (ushort*)d_ws;                       // 4 MB
    ushort* k_b = q_b + (size_t)NROWS * HD;            // 4 MB
    ushort* vtp = k_b + (size_t)NROWS * HD;            // 4 MB (v transposed [h][row])
    ushort* wt  = vtp + (size_t)HD * NROWS;            // 1.5 MB ([384][2048])
    ushort* o_part  = wt + (size_t)384 * NE;           // 32 MB (bf16 partials)
    float2* ml_part = (float2*)(o_part + (size_t)SPLITK * NROWS * HD);  // 1 MB

    wconv_kernel<<<dim3(32, 3), dim3(256), 0, stream>>>(Wq, Wk, Wv, wt);
    qkv_kernel<<<dim3(256), dim3(256), 0, stream>>>(x, wt, q_b, k_b, vtp);
    attn_kernel<<<dim3(256, SPLITK), dim3(256), 0, stream>>>(q_b, k_b, vtp, o_part, ml_part);
    combine_kernel<<<dim3((NROWS * 64) / 256), dim3(256), 0, stream>>>(
        o_part, ml_part, (float*)d_out);
}

// Round 8
// 441.069 us; speedup vs baseline: 1.3541x; 1.0416x over previous
//
#include <hip/hip_runtime.h>
#include <hip/hip_bf16.h>

#define B_SZ  4
#define T_SEQ 4096
#define NE    2048
#define HD    128
#define NROWS (B_SZ * T_SEQ)   // 16384
#define SPLITK 8

typedef __attribute__((ext_vector_type(4))) float f32x4;
typedef __attribute__((ext_vector_type(8))) short s16x8;

__device__ __forceinline__ ushort f2bf(float f) {
    __hip_bfloat16 h = __float2bfloat16(f);
    return *reinterpret_cast<ushort*>(&h);
}
__device__ __forceinline__ float bf2f(ushort u) {
    return __uint_as_float(((unsigned int)u) << 16);
}
__device__ __forceinline__ unsigned int pk2(float a, float b) {
    return (unsigned int)f2bf(a) | ((unsigned int)f2bf(b) << 16);
}

// ---------------- K0: W fp32 [2048][128] -> wt bf16 [384][2048] (B^T layout) --------
// Wq is pre-scaled by 1/sqrt(HD) so attention scores need no scale multiply.
__global__ __launch_bounds__(256) void wconv_kernel(
    const float* __restrict__ Wq, const float* __restrict__ Wk,
    const float* __restrict__ Wv, ushort* __restrict__ wt)
{
    __shared__ __align__(16) ushort tr[128][80];
    const int mat = blockIdx.y;
    const int k0  = blockIdx.x * 64;
    const float* W = (mat == 0) ? Wq : (mat == 1) ? Wk : Wv;
    const float scale = (mat == 0) ? 0.08838834764831845f : 1.0f;
    const int tid = threadIdx.x;

    #pragma unroll
    for (int p = 0; p < 32; p++) {
        const int idx = p * 256 + tid;
        const int k = idx >> 7, h = idx & 127;
        tr[h][k] = f2bf(W[(size_t)(k0 + k) * HD + h] * scale);
    }
    __syncthreads();
    const int h = tid >> 1, half = tid & 1;
    const uint4* src = (const uint4*)&tr[h][half * 32];
    uint4* dst = (uint4*)(wt + (size_t)(mat * HD + h) * NE + k0 + half * 32);
    #pragma unroll
    for (int j = 0; j < 4; j++) dst[j] = src[j];
}

// ---------------- K1: qkv = x @ [Wq|Wk|Wv], MFMA bf16, A+B LDS-staged ----------------
// block: 64 rows x 192 cols, grid (256,2) -> 2 blocks/CU. wave w: 4 mt x 3 nt
// (cols w*48..+47). Cooperative staging of x-tile (pack fp32->bf16) AND W-panel
// per k-tile: bulk loads give MLP; frags come from LDS at low latency.
__global__ __launch_bounds__(256) void qkv_kernel(
    const float* __restrict__ x, const ushort* __restrict__ wt,
    ushort* __restrict__ q_b, ushort* __restrict__ k_b, ushort* __restrict__ vt)
{
    __shared__ __align__(16) ushort xa[64][80];    // [row][k], 160B rows
    __shared__ __align__(16) ushort wb[192][80];   // [col][k], 160B rows

    const int tid  = threadIdx.x;
    const int wave = tid >> 6, lane = tid & 63;
    const int nn   = lane & 15, quad = lane >> 4;
    const int rows0 = blockIdx.x * 64;
    const int c0    = blockIdx.y * 192;
    const int cw    = wave * 48;

    f32x4 acc[4][3];
    #pragma unroll
    for (int mt = 0; mt < 4; mt++)
        #pragma unroll
        for (int nt = 0; nt < 3; nt++) acc[mt][nt] = (f32x4){0.f, 0.f, 0.f, 0.f};

    // A staging: thread -> (row, 16-wide k chunk)
    const int srow = tid >> 2, skq = tid & 3;
    const float* xp = x + (size_t)(rows0 + srow) * NE + skq * 16;
    float4 xr[4];
    auto load_x = [&](int kc) {
        #pragma unroll
        for (int j = 0; j < 4; j++) xr[j] = *(const float4*)(xp + kc + j * 4);
    };
    auto write_x = [&]() {
        uint4 w0, w1;
        w0.x = pk2(xr[0].x, xr[0].y); w0.y = pk2(xr[0].z, xr[0].w);
        w0.z = pk2(xr[1].x, xr[1].y); w0.w = pk2(xr[1].z, xr[1].w);
        w1.x = pk2(xr[2].x, xr[2].y); w1.y = pk2(xr[2].z, xr[2].w);
        w1.z = pk2(xr[3].x, xr[3].y); w1.w = pk2(xr[3].z, xr[3].w);
        *(uint4*)&xa[srow][skq * 16]     = w0;
        *(uint4*)&xa[srow][skq * 16 + 8] = w1;
    };

    // B staging: 192 rows x 64 k = 24 KB; idx = pass*256+tid -> (row, 32-el half)
    const int brow0 = tid >> 1, bh0 = (tid & 1) * 32;
    const int brow1 = (256 + tid) >> 1, bh1 = ((256 + tid) & 1) * 32;
    uint4 br[8];
    auto load_b = [&](int kc) {
        #pragma unroll
        for (int j = 0; j < 4; j++)
            br[j] = *(const uint4*)&wt[(size_t)(c0 + brow0) * NE + kc + bh0 + j * 8];
        if (tid < 128) {
            #pragma unroll
            for (int j = 0; j < 4; j++)
                br[4 + j] = *(const uint4*)&wt[(size_t)(c0 + brow1) * NE + kc + bh1 + j * 8];
        }
    };
    auto write_b = [&]() {
        #pragma unroll
        for (int j = 0; j < 4; j++) *(uint4*)&wb[brow0][bh0 + j * 8] = br[j];
        if (tid < 128) {
            #pragma unroll
            for (int j = 0; j < 4; j++) *(uint4*)&wb[brow1][bh1 + j * 8] = br[4 + j];
        }
    };

    load_x(0);
    load_b(0);
    write_x();
    write_b();

    for (int t = 0; t < 32; t++) {
        const int kc = t * 64;
        if (t + 1 < 32) { load_x(kc + 64); load_b(kc + 64); }
        __syncthreads();                 // staged writes visible
        #pragma unroll
        for (int ks = 0; ks < 2; ks++) {
            s16x8 af[4], bf[3];
            #pragma unroll
            for (int mt = 0; mt < 4; mt++)
                af[mt] = *(const s16x8*)&xa[mt * 16 + nn][ks * 32 + quad * 8];
            #pragma unroll
            for (int nt = 0; nt < 3; nt++)
                bf[nt] = *(const s16x8*)&wb[cw + nt * 16 + nn][ks * 32 + quad * 8];
            #pragma unroll
            for (int mt = 0; mt < 4; mt++)
                #pragma unroll
                for (int nt = 0; nt < 3; nt++)
                    acc[mt][nt] = __builtin_amdgcn_mfma_f32_16x16x32_bf16(
                        af[mt], bf[nt], acc[mt][nt], 0, 0, 0);
        }
        __syncthreads();                 // reads done before overwrite
        if (t + 1 < 32) { write_x(); write_b(); }
    }

    #pragma unroll
    for (int mt = 0; mt < 4; mt++)
        #pragma unroll
        for (int nt = 0; nt < 3; nt++) {
            const int c = c0 + cw + nt * 16 + nn;
            #pragma unroll
            for (int r = 0; r < 4; r++) {
                const int grow = rows0 + mt * 16 + quad * 4 + r;
                const ushort v = f2bf(acc[mt][nt][r]);
                if (c < 128)       q_b[(size_t)grow * HD + c] = v;
                else if (c < 256)  k_b[(size_t)grow * HD + (c - 128)] = v;
                else               vt[(size_t)(c - 256) * NROWS + grow] = v;
            }
        }
}

// ---------------- K2: causal flash attention, split-K, LDS-staged K/V ----------------
// 256-thread block = 4 waves sharing one (b, qgroup): wave w owns q rows
// qgroup*64 + w*16 ..+15, so ntiles = qgroup+1 is block-uniform. K/V tiles are
// cooperatively staged (reg-prefetch + 2 barriers). XCD swizzle: b = f(gx%8) so
// each XCD's L2 holds one batch's K/V (2 MB < 4 MB).
__global__ __launch_bounds__(256) void attn_kernel(
    const ushort* __restrict__ q_b, const ushort* __restrict__ k_b,
    const ushort* __restrict__ vt, ushort* __restrict__ o_part,
    float2* __restrict__ ml_part)
{
    __shared__ __align__(16) ushort kT[64][144];   // [key][h], 288B rows
    __shared__ __align__(16) ushort vT[128][80];   // [h][key], 160B rows
    __shared__ __align__(16) ushort pT[4][16][80]; // [wave][q][key]

    const int tid  = threadIdx.x;
    const int wave = tid >> 6, lane = tid & 63;
    const int nn   = lane & 15, quad = lane >> 4;

    const int gx  = blockIdx.x;                // 0..255
    const int sp  = blockIdx.y;                // 0..SPLITK-1
    const int xcd = gx & 7;
    const int b   = xcd & 3;
    const int qgroup = (gx >> 3) * 2 + (xcd >> 2);   // 0..63
    const int qrow0  = qgroup * 64 + wave * 16;
    const int qglob  = qrow0 + nn;
    const size_t bT  = (size_t)b * T_SEQ;
    const int ntiles = qgroup + 1;             // block-uniform

    s16x8 qfrag[4];
    #pragma unroll
    for (int ks = 0; ks < 4; ks++)
        qfrag[ks] = *(const s16x8*)&q_b[(bT + qrow0 + nn) * HD + ks * 32 + quad * 8];

    // staging maps: K: (key, h-chunk); V: (h, key-half)
    const int skey = tid >> 2, shc = (tid & 3) * 32;
    const int svh  = tid >> 1, svc = (tid & 1) * 32;
    uint4 kr[4], vr[4];
    auto load_stage = [&](int s0) {
        #pragma unroll
        for (int j = 0; j < 4; j++)
            kr[j] = *(const uint4*)&k_b[(bT + s0 + skey) * HD + shc + j * 8];
        #pragma unroll
        for (int j = 0; j < 4; j++)
            vr[j] = *(const uint4*)&vt[(size_t)svh * NROWS + bT + s0 + svc + j * 8];
    };
    auto write_stage = [&]() {
        #pragma unroll
        for (int j = 0; j < 4; j++) *(uint4*)&kT[skey][shc + j * 8] = kr[j];
        #pragma unroll
        for (int j = 0; j < 4; j++) *(uint4*)&vT[svh][svc + j * 8] = vr[j];
    };

    f32x4 o_acc[8];
    #pragma unroll
    for (int nt = 0; nt < 8; nt++) o_acc[nt] = (f32x4){0.f, 0.f, 0.f, 0.f};
    float m_i = -INFINITY, l_i = 0.0f;

    if (sp < ntiles) {        // block-uniform
        load_stage(sp * 64);
        write_stage();
    }

    for (int t = sp; t < ntiles; t += SPLITK) {
        const int s0 = t * 64;
        if (t + SPLITK < ntiles) load_stage((t + SPLITK) * 64);
        __syncthreads();      // staged K/V visible

        // S^T = K Q^T : lane owns q-row nn, 16 key scores (mt*16 + quad*4 + r)
        f32x4 sa[4];
        #pragma unroll
        for (int mt = 0; mt < 4; mt++) sa[mt] = (f32x4){0.f, 0.f, 0.f, 0.f};
        #pragma unroll
        for (int ks = 0; ks < 4; ks++)
            #pragma unroll
            for (int mt = 0; mt < 4; mt++) {
                const s16x8 af = *(const s16x8*)&kT[mt * 16 + nn][ks * 32 + quad * 8];
                sa[mt] = __builtin_amdgcn_mfma_f32_16x16x32_bf16(af, qfrag[ks], sa[mt], 0, 0, 0);
            }

        // causal mask — only when the tile reaches above the q rows
        if (s0 + 63 > qrow0) {
            #pragma unroll
            for (int mt = 0; mt < 4; mt++)
                #pragma unroll
                for (int r = 0; r < 4; r++)
                    if (s0 + mt * 16 + quad * 4 + r > qglob) sa[mt][r] = -INFINITY;
        }

        // online softmax: in-lane 16-value reduce + 2 cross-quad shuffles
        float rm = -INFINITY;
        #pragma unroll
        for (int mt = 0; mt < 4; mt++)
            #pragma unroll
            for (int r = 0; r < 4; r++) rm = fmaxf(rm, sa[mt][r]);
        rm = fmaxf(rm, __shfl_xor(rm, 16));
        rm = fmaxf(rm, __shfl_xor(rm, 32));
        const float mnew = fmaxf(m_i, rm);
        const float alpha = __expf(m_i - mnew);
        m_i = mnew;

        float p[4][4], rs = 0.0f;
        #pragma unroll
        for (int mt = 0; mt < 4; mt++)
            #pragma unroll
            for (int r = 0; r < 4; r++) {
                p[mt][r] = __expf(sa[mt][r] - mnew);
                rs += p[mt][r];
            }
        rs += __shfl_xor(rs, 16);
        rs += __shfl_xor(rs, 32);
        l_i = l_i * alpha + rs;

        // P -> LDS in A-layout rows: pT[wave][q=nn][key]
        #pragma unroll
        for (int mt = 0; mt < 4; mt++) {
            uint2 w;
            w.x = pk2(p[mt][0], p[mt][1]);
            w.y = pk2(p[mt][2], p[mt][3]);
            *(uint2*)&pT[wave][nn][mt * 16 + quad * 4] = w;
        }

        // broadcast alpha to O rows (row m = quad*4+r lives in lane m's softmax)
        float am[4];
        #pragma unroll
        for (int r = 0; r < 4; r++) am[r] = __shfl(alpha, quad * 4 + r);
        #pragma unroll
        for (int nt = 0; nt < 8; nt++) {
            o_acc[nt][0] *= am[0];
            o_acc[nt][1] *= am[1];
            o_acc[nt][2] *= am[2];
            o_acc[nt][3] *= am[3];
        }

        // O += P V
        s16x8 pf[2];
        pf[0] = *(const s16x8*)&pT[wave][nn][quad * 8];
        pf[1] = *(const s16x8*)&pT[wave][nn][32 + quad * 8];
        #pragma unroll
        for (int nt = 0; nt < 8; nt++)
            #pragma unroll
            for (int kst = 0; kst < 2; kst++) {
                const s16x8 vb = *(const s16x8*)&vT[nt * 16 + nn][kst * 32 + quad * 8];
                o_acc[nt] = __builtin_amdgcn_mfma_f32_16x16x32_bf16(pf[kst], vb, o_acc[nt], 0, 0, 0);
            }

        __syncthreads();      // all reads done before next overwrite
        if (t + SPLITK < ntiles) write_stage();
    }

    // write partials (unnormalized O as bf16 + per-row m,l)
    ushort* op = o_part + ((size_t)sp * NROWS + bT + qrow0 + quad * 4) * HD + nn;
    #pragma unroll
    for (int r = 0; r < 4; r++)
        #pragma unroll
        for (int nt = 0; nt < 8; nt++)
            op[(size_t)r * HD + nt * 16] = f2bf(o_acc[nt][r]);
    if (quad == 0)
        ml_part[(size_t)sp * NROWS + bT + qrow0 + nn] = make_float2(m_i, l_i);
}

// ---------------- K3: split-K combine ----------------
__global__ __launch_bounds__(256) void combine_kernel(
    const ushort* __restrict__ o_part, const float2* __restrict__ ml_part,
    float* __restrict__ out)
{
    const int idx = blockIdx.x * 256 + threadIdx.x;  // NROWS*64 threads
    const int row = idx >> 6;
    const int c   = (idx & 63) * 2;

    float m[SPLITK], l[SPLITK];
    float M = -INFINITY;
    #pragma unroll
    for (int s = 0; s < SPLITK; s++) {
        const float2 t = ml_part[(size_t)s * NROWS + row];
        m[s] = t.x; l[s] = t.y;
        M = fmaxf(M, m[s]);
    }
    float L = 0.0f, w[SPLITK];
    #pragma unroll
    for (int s = 0; s < SPLITK; s++) {
        w[s] = __expf(m[s] - M);
        L += w[s] * l[s];
    }
    const float inv = 1.0f / L;
    float ox = 0.0f, oy = 0.0f;
    #pragma unroll
    for (int s = 0; s < SPLITK; s++) {
        const ushort* po = o_part + ((size_t)s * NROWS + row) * HD + c;
        ox += w[s] * bf2f(po[0]);
        oy += w[s] * bf2f(po[1]);
    }
    out[(size_t)row * HD + c]     = ox * inv;
    out[(size_t)row * HD + c + 1] = oy * inv;
}

extern "C" void kernel_launch(void* const* d_in, const int* in_sizes, int n_in,
                              void* d_out, int out_size, void* d_ws, size_t ws_size,
                              hipStream_t stream) {
    const float* x  = (const float*)d_in[0];
    const float* Wq = (const float*)d_in[1];
    const float* Wk = (const float*)d_in[2];
    const float* Wv = (const float*)d_in[3];

    ushort* q_b = (ushort*)d_ws;                       // 4 MB
    ushort* k_b = q_b + (size_t)NROWS * HD;            // 4 MB
    ushort* vtp = k_b + (size_t)NROWS * HD;            // 4 MB (v transposed [h][row])
    ushort* wt  = vtp + (size_t)HD * NROWS;            // 1.5 MB ([384][2048])
    ushort* o_part  = wt + (size_t)384 * NE;           // 32 MB (bf16 partials)
    float2* ml_part = (float2*)(o_part + (size_t)SPLITK * NROWS * HD);  // 1 MB

    wconv_kernel<<<dim3(32, 3), dim3(256), 0, stream>>>(Wq, Wk, Wv, wt);
    qkv_kernel<<<dim3(256, 2), dim3(256), 0, stream>>>(x, wt, q_b, k_b, vtp);
    attn_kernel<<<dim3(256, SPLITK), dim3(256), 0, stream>>>(q_b, k_b, vtp, o_part, ml_part);
    combine_kernel<<<dim3((NROWS * 64) / 256), dim3(256), 0, stream>>>(
        o_part, ml_part, (float*)d_out);
}